// Round 3
// baseline (555.401 us; speedup 1.0000x reference)
//
#include <hip/hip_runtime.h>
#include <math.h>

// Quantum circuit sim, 20 qubits, 4 layers, batch 16, purely-real f32 state.
// Element bit Ek <-> qubit q = 19-k. 7 fused passes (R A F L A* F* L*), same
// gate/layout math as the verified 282-us kernel, restructured as a two-tile
// software pipeline per block:
//   - grid 512, each block runs tile blockIdx.x then tile blockIdx.x+512
//   - both tiles' global loads issued up front (64 data VGPRs)
//   - raw s_barrier + lgkmcnt(0) (NO vmcnt drain) so tile-1 loads stream under
//     tile-0 compute and tile-0 stores retire under tile-1 compute.
// M/P/Q inter-pass layouts: dense float4 per lane. LDS swizzles <=2-way.

__global__ void cs_kernel(const float* __restrict__ theta, float2* __restrict__ cs) {
    int i = threadIdx.x;
    if (i < 80) {
        float s, c;
        sincosf(theta[i] * 0.5f, &s, &c);
        cs[i] = make_float2(c, s);
    }
}

// barrier: LDS producer-drain + workgroup barrier, vmcnt left untouched
#define BAR() { asm volatile("s_waitcnt lgkmcnt(0)" ::: "memory"); __builtin_amdgcn_s_barrier(); }

// RY on fragment bit MASK of array V with angle table TBL[Q]
#define RYV_(V, TBL, MASK, Q) { float2 _sc = (TBL)[(Q)]; float _c = _sc.x, _s = _sc.y; \
  _Pragma("unroll") for (int _m = 0; _m < 32; ++_m) if (!(_m & (MASK))) { \
    float _a = (V)[_m], _b = (V)[_m | (MASK)]; \
    (V)[_m] = _c*_a - _s*_b; (V)[_m | (MASK)] = _s*_a + _c*_b; } }

// CNOT: control mask CM, target mask TM, both in fragment
#define CXV_(V, CM, TM) { _Pragma("unroll") for (int _m = 0; _m < 32; ++_m) \
  if ((_m & (CM)) && !(_m & (TM))) { float _t = (V)[_m]; (V)[_m] = (V)[_m|(TM)]; (V)[_m|(TM)] = _t; } }

// CNOT with control on a thread-index bit (COND), target mask TM in fragment
#define CXIV_(V, COND, TM) { if (COND) { _Pragma("unroll") for (int _m = 0; _m < 32; ++_m) \
  if (!(_m & (TM))) { float _t = (V)[_m]; (V)[_m] = (V)[_m|(TM)]; (V)[_m|(TM)] = _t; } } }

__device__ __forceinline__ int mixR(int n) {
    return ((n >> 5) & 31) ^ ((n >> 10) & 1);
}
__device__ __forceinline__ int mixA(int n) {
    return ((n >> 5) & 31) ^ ((n >> 10) & 1) ^ (((n >> 11) & 1) << 3)
         ^ (((n >> 12) & 1) << 4) ^ (((n >> 13) & 1) << 4);
}
__device__ __forceinline__ int mixF(int n) {
    return ((n >> 5) & 31) ^ (((n >> 10) & 1) << 1) ^ (((n >> 11) & 1) << 2)
         ^ (((n >> 12) & 1) << 3) ^ (((n >> 13) & 1) << 4);
}
__device__ __forceinline__ int mixL(int n) {
    return ((n >> 5) & 31) ^ (((n >> 10) & 1) << 4) ^ (((n >> 11) & 1) << 2)
         ^ (((n >> 12) & 1) << 3) ^ (((n >> 13) & 1) << 4);
}

// ---------------- Pass R: std -> M, RY on E13..E0 (layer 0) ----------------
// n: [n0..n4]=(E0,E1,E10,E11,E12) [n5..n10]=(E2..E7) [n11..n13]=(E8,E9,E13)
#define R_LOAD(BLK, V) { int H = (BLK) & 63, b = (BLK) >> 6; \
  int base = (b << 18) + (H << 12); \
  _Pragma("unroll") for (int i = 0; i < 8; ++i) { \
    float4 w = src[base + (i << 8) + (((t >> 6) & 3) << 6) + (((t >> 8) & 1) << 11) + (t & 63)]; \
    (V)[i*4+0] = w.x; (V)[i*4+1] = w.y; (V)[i*4+2] = w.z; (V)[i*4+3] = w.w; } }

#define R_PH1(V) { \
  RYV_(V, csl, 1, 19); RYV_(V, csl, 2, 18); RYV_(V, csl, 4, 9); RYV_(V, csl, 8, 8); RYV_(V, csl, 16, 7); \
  int w1x = (t & 31) ^ ((t >> 5) & 1); \
  _Pragma("unroll") for (int m = 0; m < 32; ++m) lds[(t << 5) | (m ^ w1x)] = (V)[m]; }

#define R_PH2(V) { int tp = (t & 31) | (((t >> 5) & 1) << 10) | (((t >> 6) & 7) << 11); \
  int mt = mixR(tp); \
  _Pragma("unroll") for (int f = 0; f < 32; ++f) { int fc = f << 5; (V)[f] = lds[(tp | fc) ^ mt ^ mixR(fc)]; } \
  RYV_(V, csl, 1, 17); RYV_(V, csl, 2, 16); RYV_(V, csl, 4, 15); RYV_(V, csl, 8, 14); RYV_(V, csl, 16, 13); \
  _Pragma("unroll") for (int f = 0; f < 32; ++f) { int fc = f << 5; lds[(tp | fc) ^ mt ^ mixR(fc)] = (V)[f]; } }

#define R_PH3(V, BLK) { int tp = ((t & 1) << 2) | (((t >> 1) & 1) << 3) | (((t >> 2) & 1) << 4) \
             | (((t >> 3) & 1) << 5) | (((t >> 4) & 1) << 1) | (((t >> 5) & 1) << 0) \
             | (((t >> 6) & 7) << 6); \
  int mt = mixR(tp); \
  _Pragma("unroll") for (int p = 0; p < 32; ++p) { int fc = p << 9; (V)[p] = lds[(tp | fc) ^ mt ^ mixR(fc)]; } \
  RYV_(V, csl, 2, 12); RYV_(V, csl, 4, 11); RYV_(V, csl, 8, 10); RYV_(V, csl, 16, 6); \
  int H = (BLK) & 63, b = (BLK) >> 6; \
  int sb = (b << 18) + (H << 12) + (((t >> 6) & 7) << 6) + (t & 63); \
  _Pragma("unroll") for (int j = 0; j < 8; ++j) \
    dst[sb + (j << 9)] = make_float4((V)[4*j], (V)[4*j+1], (V)[4*j+2], (V)[4*j+3]); }

__global__ __launch_bounds__(512, 4) void pass_R(
    const float4* __restrict__ src, float4* __restrict__ dst,
    const float2* __restrict__ cs)
{
    __shared__ float lds[16384];
    const float2* csl = cs;                       // layer 0
    int t = threadIdx.x;
    int blk0 = blockIdx.x, blk1 = blockIdx.x + 512;
    float va[32], vb[32];

    R_LOAD(blk0, va); R_LOAD(blk1, vb);
    R_PH1(va); BAR();
    R_PH2(va); BAR();
    R_PH3(va, blk0); BAR();
    R_PH1(vb); BAR();
    R_PH2(vb); BAR();
    R_PH3(vb, blk1);
}

// ---------------- Pass A: M -> P ----------------
// n: [n0..n4]=(E6,E7,E17,E18,E19) [n5..n10]=(E10,E11,E12,E14,E15,E16)
//    [n11..n13]=(E8,E9,E13)
#define A_LOAD(BLK, V) { int G = (BLK) & 63, b = (BLK) >> 6; \
  int Gperm = ((G >> 2) & 1) | (((G >> 1) & 1) << 1) | ((G & 1) << 2) | (((G >> 3) & 7) << 3); \
  int lb = (b << 18) + (((t >> 6) & 7) << 9) + (Gperm << 3) + (t & 7); \
  int rg = ((t >> 3) & 7) << 12; \
  _Pragma("unroll") for (int i = 0; i < 8; ++i) { \
    float4 w = src[lb + ((i << 3) << 12) + rg]; \
    (V)[i*4+0] = w.x; (V)[i*4+1] = w.y; (V)[i*4+2] = w.z; (V)[i*4+3] = w.w; } }

#define A_PH1(V) { \
  RYV_(V, csl, 16, 0); RYV_(V, csl, 8, 1); RYV_(V, csl, 4, 2); \
  if (FULL) { RYV_(V, csl, 2, 12); RYV_(V, csl, 1, 13); } \
  int w1x = (t & 31) ^ ((t >> 5) & 1) ^ (((t >> 6) & 1) << 3) \
          ^ (((t >> 7) & 1) << 4) ^ (((t >> 8) & 1) << 4); \
  _Pragma("unroll") for (int m = 0; m < 32; ++m) lds[(t << 5) | (m ^ w1x)] = (V)[m]; }

#define A_PH2(V) { int tp = (t & 3) | (((t >> 2) & 1) << 7) | (((t >> 3) & 1) << 11) \
             | (((t >> 4) & 1) << 12) | (((t >> 5) & 1) << 13) | (((t >> 6) & 1) << 5) \
             | (((t >> 7) & 1) << 6) | (((t >> 8) & 1) << 8); \
  int mt = mixA(tp); \
  _Pragma("unroll") for (int f = 0; f < 32; ++f) { \
    int fc = ((f & 1) << 9) | (((f >> 1) & 1) << 10) | (((f >> 2) & 1) << 2) \
           | (((f >> 3) & 1) << 3) | (((f >> 4) & 1) << 4); \
    (V)[f] = lds[(tp | fc) ^ mt ^ mixA(fc)]; } \
  RYV_(V, csl, 1, 4); RYV_(V, csl, 2, 3); \
  CXV_(V, 16, 8); CXV_(V, 8, 4); CXV_(V, 4, 2); CXV_(V, 2, 1); \
  _Pragma("unroll") for (int f = 0; f < 32; ++f) { \
    int fc = ((f & 1) << 9) | (((f >> 1) & 1) << 10) | (((f >> 2) & 1) << 2) \
           | (((f >> 3) & 1) << 3) | (((f >> 4) & 1) << 4); \
    lds[(tp | fc) ^ mt ^ mixA(fc)] = (V)[f]; } }

#define A_PH3(V) { int tp = (t & 31) | (((t >> 5) & 1) << 9) | (((t >> 6) & 1) << 10) \
             | (((t >> 7) & 1) << 11) | (((t >> 8) & 1) << 12); \
  int mt = mixA(tp); \
  _Pragma("unroll") for (int f = 0; f < 32; ++f) { \
    int fc = ((f & 1) << 5) | (((f >> 1) & 1) << 6) | (((f >> 2) & 1) << 7) \
           | (((f >> 3) & 1) << 13) | (((f >> 4) & 1) << 8); \
    (V)[f] = lds[(tp | fc) ^ mt ^ mixA(fc)]; } \
  RYV_(V, csl, 16, 5); \
  if (FULL) { RYV_(V, csl, 8, 6); RYV_(V, csl, 4, 7); RYV_(V, csl, 2, 8); RYV_(V, csl, 1, 9); } \
  CXIV_(V, (t >> 5) & 1, 16); CXV_(V, 16, 8); CXV_(V, 8, 4); CXV_(V, 4, 2); CXV_(V, 2, 1); \
  _Pragma("unroll") for (int f = 0; f < 32; ++f) { \
    int fc = ((f & 1) << 5) | (((f >> 1) & 1) << 6) | (((f >> 2) & 1) << 7) \
           | (((f >> 3) & 1) << 13) | (((f >> 4) & 1) << 8); \
    lds[(tp | fc) ^ mt ^ mixA(fc)] = (V)[f]; } }

#define A_PH4(V, BLK) { int tp = ((t & 1) << 8) | (((t >> 1) & 1) << 9) | (((t >> 2) & 1) << 10) \
             | (((t >> 3) & 1) << 6) | (((t >> 4) & 1) << 7) | (((t >> 5) & 1) << 2) \
             | (((t >> 6) & 1) << 5) | (((t >> 7) & 1) << 3) | (((t >> 8) & 1) << 4); \
  int mt = mixA(tp); \
  _Pragma("unroll") for (int p = 0; p < 32; ++p) { \
    int fc = ((p & 1) << 0) | (((p >> 1) & 1) << 13) | (((p >> 2) & 1) << 1) \
           | (((p >> 3) & 1) << 11) | (((p >> 4) & 1) << 12); \
    (V)[p] = lds[(tp | fc) ^ mt ^ mixA(fc)]; } \
  if (FULL) { RYV_(V, csl, 16, 10); RYV_(V, csl, 8, 11); } \
  CXIV_(V, (t >> 6) & 1, 16); CXV_(V, 16, 8); CXV_(V, 8, 4); CXV_(V, 4, 1); \
  int G = (BLK) & 63, b = (BLK) >> 6; \
  int sb = (b << 18) + (G << 12) + t; \
  _Pragma("unroll") for (int j = 0; j < 8; ++j) \
    dst[sb + (j << 9)] = make_float4((V)[4*j], (V)[4*j+1], (V)[4*j+2], (V)[4*j+3]); }

template <bool FULL>
__global__ __launch_bounds__(512, 4) void pass_A(
    const float4* __restrict__ src, float4* __restrict__ dst,
    const float2* __restrict__ cs, int layer)
{
    __shared__ float lds[16384];
    const float2* csl = cs + layer * 20;
    int t = threadIdx.x;
    int blk0 = blockIdx.x, blk1 = blockIdx.x + 512;
    float va[32], vb[32];

    A_LOAD(blk0, va); A_LOAD(blk1, vb);
    A_PH1(va); BAR();
    A_PH2(va); BAR();
    A_PH3(va); BAR();
    A_PH4(va, blk0); BAR();
    A_PH1(vb); BAR();
    A_PH2(vb); BAR();
    A_PH3(vb); BAR();
    A_PH4(vb, blk1);
}

// ---------------- Pass F: P -> Q ----------------
// n: [n0..n4]=(E6,E13,E17,E18,E19) [n5..n10]=(E14,E15,E16,E0,E1,E2)
//    [n11..n13]=(E3,E4,E5)
#define F_LOAD(BLK, V) { int W = (BLK) & 63, b = (BLK) >> 6; \
  int Wp = (((W >> 4) & 1) << 3) | (((W >> 5) & 1) << 4) | (((W >> 3) & 1) << 6) \
         | ((W & 1) << 9) | (((W >> 1) & 1) << 10) | (((W >> 2) & 1) << 11); \
  int lb = (((b << 6) | ((t >> 3) & 63)) << 12) + (t & 7) + Wp; \
  _Pragma("unroll") for (int i = 0; i < 8; ++i) { \
    float4 w = src[lb + ((i & 1) << 5) + (((i >> 1) & 1) << 7) + (((i >> 2) & 1) << 8)]; \
    (V)[i*4+0] = w.x; (V)[i*4+1] = w.y; (V)[i*4+2] = w.z; (V)[i*4+3] = w.w; } }

#define F_PH1(V) { \
  RYV_(V, csl2, 16, 0); RYV_(V, csl2, 8, 1); RYV_(V, csl2, 4, 2); RYV_(V, csl2, 2, 6); \
  CXV_(V, 16, 8); CXV_(V, 8, 4); \
  int w1x = (t & 31) ^ (((t >> 5) & 1) << 1) ^ (((t >> 6) & 1) << 2) \
          ^ (((t >> 7) & 1) << 3) ^ (((t >> 8) & 1) << 4); \
  _Pragma("unroll") for (int m = 0; m < 32; ++m) lds[(t << 5) | (m ^ w1x)] = (V)[m]; }

#define F_PH2(V) { int tp = (t & 31) | (((t >> 5) & 1) << 8) | (((t >> 6) & 1) << 5) \
             | (((t >> 7) & 1) << 6) | (((t >> 8) & 1) << 7); \
  int mt = mixF(tp); \
  _Pragma("unroll") for (int f = 0; f < 32; ++f) { int fc = f << 9; (V)[f] = lds[(tp | fc) ^ mt ^ mixF(fc)]; } \
  if (LOWRY) { RYV_(V, csl, 16, 14); RYV_(V, csl, 8, 15); RYV_(V, csl, 4, 16); RYV_(V, csl, 2, 17); RYV_(V, csl, 1, 18); } \
  CXIV_(V, t & 1, 16); CXV_(V, 16, 8); CXV_(V, 8, 4); CXV_(V, 4, 2); CXV_(V, 2, 1); \
  _Pragma("unroll") for (int f = 0; f < 32; ++f) { int fc = f << 9; lds[(tp | fc) ^ mt ^ mixF(fc)] = (V)[f]; } }

#define F_PH3(V, BLK) { int tp = ((t & 1) << 12) | (((t >> 1) & 1) << 13) | (((t >> 2) & 1) << 0) \
             | (((t >> 3) & 1) << 9) | (((t >> 4) & 1) << 10) | (((t >> 5) & 1) << 11) \
             | (((t >> 6) & 1) << 2) | (((t >> 7) & 1) << 3) | (((t >> 8) & 1) << 4); \
  int mt = mixF(tp); \
  _Pragma("unroll") for (int p = 0; p < 32; ++p) { \
    int fc = ((p & 1) << 8) | (((p >> 1) & 1) << 1) | (((p >> 2) & 1) << 5) \
           | (((p >> 3) & 1) << 6) | (((p >> 4) & 1) << 7); \
    (V)[p] = lds[(tp | fc) ^ mt ^ mixF(fc)]; } \
  if (LOWRY) { RYV_(V, csl, 1, 19); } \
  CXIV_(V, (t >> 3) & 1, 1); \
  RYV_(V, csl2, 16, 3); RYV_(V, csl2, 8, 4); RYV_(V, csl2, 4, 5); \
  CXIV_(V, (t >> 6) & 1, 16); CXV_(V, 16, 8); CXV_(V, 8, 4); CXV_(V, 4, 2); \
  int sb = ((BLK) << 12) + t; \
  _Pragma("unroll") for (int j = 0; j < 8; ++j) \
    dst[sb + (j << 9)] = make_float4((V)[4*j], (V)[4*j+1], (V)[4*j+2], (V)[4*j+3]); }

template <bool LOWRY>
__global__ __launch_bounds__(512, 4) void pass_F(
    const float4* __restrict__ src, float4* __restrict__ dst,
    const float2* __restrict__ cs, int layer)
{
    __shared__ float lds[16384];
    const float2* csl  = cs + layer * 20;         // layer l (low chain / low RY)
    const float2* csl2 = cs + (layer + 1) * 20;   // layer l+1 (hi RY + hi chain)
    int t = threadIdx.x;
    int blk0 = blockIdx.x, blk1 = blockIdx.x + 512;
    float va[32], vb[32];

    F_LOAD(blk0, va); F_LOAD(blk1, vb);
    F_PH1(va); BAR();
    F_PH2(va); BAR();
    F_PH3(va, blk0); BAR();
    F_PH1(vb); BAR();
    F_PH2(vb); BAR();
    F_PH3(vb, blk1);
}

// ---------------- Pass L: Q -> M (mid) or std+abs (fin) ----------------
// n: [n0..n4]=(E0,E13,E10,E11,E12) [n5..n10]=(E4,E5,E6,E1,E2,E3)
//    [n11..n13]=(E7,E8,E9)
#define L_LOAD(BLK, V) { int H = (BLK) & 63, b = (BLK) >> 6; \
  int Hp = (((H >> 3) & 7) << 6) | ((H & 7) << 9); \
  int rb = (b << 6) | ((t >> 6) & 7); \
  int lo = Hp + (t & 63); \
  _Pragma("unroll") for (int i = 0; i < 8; ++i) { \
    float4 w = src[((rb | (i << 3)) << 12) + lo]; \
    (V)[i*4+0] = w.x; (V)[i*4+1] = w.y; (V)[i*4+2] = w.z; (V)[i*4+3] = w.w; } }

#define L_PH1(V) { \
  RYV_(V, csl, 1, 19); RYV_(V, csl, 4, 9); RYV_(V, csl, 8, 8); RYV_(V, csl, 16, 7); \
  int w1x = (t & 31) ^ (((t >> 5) & 1) << 4) ^ (((t >> 6) & 1) << 2) \
          ^ (((t >> 7) & 1) << 3) ^ (((t >> 8) & 1) << 4); \
  _Pragma("unroll") for (int m = 0; m < 32; ++m) lds[(t << 5) | (m ^ w1x)] = (V)[m]; }

#define L_PH2(V) { int tp = (t & 3) | (((t >> 2) & 1) << 7) | (((t >> 3) & 1) << 8) \
             | (((t >> 4) & 1) << 9) | (((t >> 5) & 1) << 10) | (((t >> 6) & 1) << 5) \
             | (((t >> 7) & 1) << 6) | (((t >> 8) & 1) << 11); \
  int mt = mixL(tp); \
  _Pragma("unroll") for (int f = 0; f < 32; ++f) { \
    int fc = ((f & 1) << 12) | (((f >> 1) & 1) << 13) | (((f >> 2) & 1) << 2) \
           | (((f >> 3) & 1) << 3) | (((f >> 4) & 1) << 4); \
    (V)[f] = lds[(tp | fc) ^ mt ^ mixL(fc)]; } \
  RYV_(V, csl, 2, 10); RYV_(V, csl, 1, 11); \
  CXIV_(V, (t >> 1) & 1, 16); CXV_(V, 16, 8); CXV_(V, 8, 4); CXV_(V, 4, 2); CXV_(V, 2, 1); \
  _Pragma("unroll") for (int f = 0; f < 32; ++f) { \
    int fc = ((f & 1) << 12) | (((f >> 1) & 1) << 13) | (((f >> 2) & 1) << 2) \
           | (((f >> 3) & 1) << 3) | (((f >> 4) & 1) << 4); \
    lds[(tp | fc) ^ mt ^ mixL(fc)] = (V)[f]; } }

#define L_PH3(V) { int tp = (t & 31) | (((t >> 5) & 1) << 9) | (((t >> 6) & 1) << 8) \
             | (((t >> 7) & 1) << 12) | (((t >> 8) & 1) << 13); \
  int mt = mixL(tp); \
  _Pragma("unroll") for (int f = 0; f < 32; ++f) { \
    int fc = ((f & 1) << 10) | (((f >> 1) & 1) << 5) | (((f >> 2) & 1) << 6) \
           | (((f >> 3) & 1) << 7) | (((f >> 4) & 1) << 11); \
    (V)[f] = lds[(tp | fc) ^ mt ^ mixL(fc)]; } \
  RYV_(V, csl, 16, 12); RYV_(V, csl, 8, 13); RYV_(V, csl, 4, 14); RYV_(V, csl, 2, 15); RYV_(V, csl, 1, 16); \
  CXIV_(V, (t >> 7) & 1, 16); CXV_(V, 16, 8); CXV_(V, 8, 4); CXV_(V, 4, 2); CXV_(V, 2, 1); \
  _Pragma("unroll") for (int f = 0; f < 32; ++f) { \
    int fc = ((f & 1) << 10) | (((f >> 1) & 1) << 5) | (((f >> 2) & 1) << 6) \
           | (((f >> 3) & 1) << 7) | (((f >> 4) & 1) << 11); \
    lds[(tp | fc) ^ mt ^ mixL(fc)] = (V)[f]; } }

#define L_PH4(V, BLK) { int tp; \
  if (!FIN) \
    tp = ((t & 1) << 2) | (((t >> 1) & 1) << 3) | (((t >> 2) & 1) << 4) \
       | (((t >> 3) & 1) << 10) | (((t >> 4) & 1) << 5) | (((t >> 5) & 1) << 6) \
       | (((t >> 6) & 1) << 1) | (((t >> 7) & 1) << 12) | (((t >> 8) & 1) << 13); \
  else \
    tp = ((t & 1) << 10) | (((t >> 1) & 1) << 5) | (((t >> 2) & 1) << 6) \
       | (((t >> 3) & 1) << 12) | (((t >> 4) & 1) << 13) | (((t >> 5) & 1) << 2) \
       | (((t >> 6) & 1) << 1) | (((t >> 7) & 1) << 3) | (((t >> 8) & 1) << 4); \
  int mt = mixL(tp); \
  _Pragma("unroll") for (int u = 0; u < 32; ++u) { \
    int fc = ((u & 1) << 0) | (((u >> 1) & 1) << 8) | (((u >> 2) & 1) << 9) \
           | (((u >> 3) & 1) << 7) | (((u >> 4) & 1) << 11); \
    (V)[u] = lds[(tp | fc) ^ mt ^ mixL(fc)]; } \
  RYV_(V, csl, 4, 17); RYV_(V, csl, 2, 18); \
  { int e3 = FIN ? (t & 1) : ((t >> 3) & 1); \
    CXIV_(V, e3, 4); } \
  CXV_(V, 4, 2); CXV_(V, 2, 1); \
  if (!FIN) { \
    int sb = ((BLK) << 12) + (t & 7) + (((t >> 3) & 7) << 6) \
           + (((t >> 7) & 3) << 9) + (((t >> 6) & 1) << 11); \
    _Pragma("unroll") for (int g = 0; g < 8; ++g) { \
      int bu = ((g >> 2) & 1) | (((g >> 1) & 1) << 1) | ((g & 1) << 2); \
      dst[sb + (g << 3)] = make_float4((V)[bu], (V)[bu | 8], (V)[bu | 16], (V)[bu | 24]); \
    } \
  } else { \
    int sb = ((BLK) << 12) + ((t & 7) << 1) + (((t >> 3) & 7) << 6) \
           + (((t >> 7) & 1) << 9) + (((t >> 8) & 1) << 10) + (((t >> 6) & 1) << 11); \
    _Pragma("unroll") for (int g = 0; g < 8; ++g) { \
      int bu = ((g & 1) << 2) | (((g >> 1) & 1) << 3) | (((g >> 2) & 1) << 4); \
      dst[sb + (g & 1) + (((g >> 1) & 1) << 4) + (((g >> 2) & 1) << 5)] = \
        make_float4(fabsf((V)[bu]), fabsf((V)[bu | 1]), fabsf((V)[bu | 2]), fabsf((V)[bu | 3])); \
    } \
  } }

template <bool FIN>
__global__ __launch_bounds__(512, 4) void pass_L(
    const float4* __restrict__ src, float4* __restrict__ dst,
    const float2* __restrict__ cs, int layer)
{
    __shared__ float lds[16384];
    const float2* csl = cs + layer * 20;
    int t = threadIdx.x;
    int blk0 = blockIdx.x, blk1 = blockIdx.x + 512;
    float va[32], vb[32];

    L_LOAD(blk0, va); L_LOAD(blk1, vb);
    L_PH1(va); BAR();
    L_PH2(va); BAR();
    L_PH3(va); BAR();
    L_PH4(va, blk0); BAR();
    L_PH1(vb); BAR();
    L_PH2(vb); BAR();
    L_PH3(vb); BAR();
    L_PH4(vb, blk1);
}

extern "C" void kernel_launch(void* const* d_in, const int* in_sizes, int n_in,
                              void* d_out, int out_size, void* d_ws, size_t ws_size,
                              hipStream_t stream) {
    const float* x     = (const float*)d_in[0];   // (16, 2^20) f32, standard layout
    const float* theta = (const float*)d_in[1];   // (80,) f32
    float2* cs = (float2*)d_ws;                   // 80 (cos,sin) pairs
    float4* wsS = (float4*)((char*)d_ws + 4096);  // 64 MB scratch state
    float4* out = (float4*)d_out;

    cs_kernel<<<1, 128, 0, stream>>>(theta, cs);

    dim3 grid(512), block(512);
    pass_R<<<grid, block, 0, stream>>>((const float4*)x, out, cs);            // L0 lo-RY
    pass_A<false><<<grid, block, 0, stream>>>(out, wsS, cs, 0);               // L0 hi
    pass_F<false><<<grid, block, 0, stream>>>(wsS, out, cs, 0);               // L0 lo-chain + L1 hi
    pass_L<false><<<grid, block, 0, stream>>>(out, wsS, cs, 1);               // L1 lo
    pass_A<true><<<grid, block, 0, stream>>>(wsS, out, cs, 2);                // L2 hi (full RY)
    pass_F<true><<<grid, block, 0, stream>>>(out, wsS, cs, 2);                // L2 lo + L3 hi
    pass_L<true><<<grid, block, 0, stream>>>(wsS, out, cs, 3);                // L3 lo + abs
}

// Round 4
// 337.665 us; speedup vs baseline: 1.6448x; 1.6448x over previous
//
#include <hip/hip_runtime.h>
#include <math.h>

// Quantum circuit sim, 20 qubits, 4 layers, batch 16, purely-real f32 state.
// Element bit Ek <-> qubit q = 19-k. 7 fused passes (R A F L A* F* L*), same
// gate/layout math as the verified 282-us kernel, restructured as a two-tile
// software pipeline per block:
//   - grid 512, each block runs tile blockIdx.x then tile blockIdx.x+512
//   - both tiles' global loads issued up front (64 data VGPRs)
//   - raw s_barrier + lgkmcnt(0) (NO vmcnt drain) so tile-1 loads stream under
//     tile-0 compute and tile-0 stores retire under tile-1 compute.
//   - __launch_bounds__(512, 2): LDS (64KB) caps occupancy at 2 blocks/CU
//     anyway; min-waves=2 lets the allocator use up to 256 VGPR so the 64
//     live data floats do NOT spill (R3: min-waves=4 made the compiler target
//     64 VGPR -> vb[] spilled to scratch -> +121MB/pass HBM traffic, 2x slow).
// M/P/Q inter-pass layouts: dense float4 per lane. LDS swizzles <=2-way.

__global__ void cs_kernel(const float* __restrict__ theta, float2* __restrict__ cs) {
    int i = threadIdx.x;
    if (i < 80) {
        float s, c;
        sincosf(theta[i] * 0.5f, &s, &c);
        cs[i] = make_float2(c, s);
    }
}

// barrier: LDS producer-drain + workgroup barrier, vmcnt left untouched
#define BAR() { asm volatile("s_waitcnt lgkmcnt(0)" ::: "memory"); __builtin_amdgcn_s_barrier(); }

// RY on fragment bit MASK of array V with angle table TBL[Q]
#define RYV_(V, TBL, MASK, Q) { float2 _sc = (TBL)[(Q)]; float _c = _sc.x, _s = _sc.y; \
  _Pragma("unroll") for (int _m = 0; _m < 32; ++_m) if (!(_m & (MASK))) { \
    float _a = (V)[_m], _b = (V)[_m | (MASK)]; \
    (V)[_m] = _c*_a - _s*_b; (V)[_m | (MASK)] = _s*_a + _c*_b; } }

// CNOT: control mask CM, target mask TM, both in fragment
#define CXV_(V, CM, TM) { _Pragma("unroll") for (int _m = 0; _m < 32; ++_m) \
  if ((_m & (CM)) && !(_m & (TM))) { float _t = (V)[_m]; (V)[_m] = (V)[_m|(TM)]; (V)[_m|(TM)] = _t; } }

// CNOT with control on a thread-index bit (COND), target mask TM in fragment
#define CXIV_(V, COND, TM) { if (COND) { _Pragma("unroll") for (int _m = 0; _m < 32; ++_m) \
  if (!(_m & (TM))) { float _t = (V)[_m]; (V)[_m] = (V)[_m|(TM)]; (V)[_m|(TM)] = _t; } } }

__device__ __forceinline__ int mixR(int n) {
    return ((n >> 5) & 31) ^ ((n >> 10) & 1);
}
__device__ __forceinline__ int mixA(int n) {
    return ((n >> 5) & 31) ^ ((n >> 10) & 1) ^ (((n >> 11) & 1) << 3)
         ^ (((n >> 12) & 1) << 4) ^ (((n >> 13) & 1) << 4);
}
__device__ __forceinline__ int mixF(int n) {
    return ((n >> 5) & 31) ^ (((n >> 10) & 1) << 1) ^ (((n >> 11) & 1) << 2)
         ^ (((n >> 12) & 1) << 3) ^ (((n >> 13) & 1) << 4);
}
__device__ __forceinline__ int mixL(int n) {
    return ((n >> 5) & 31) ^ (((n >> 10) & 1) << 4) ^ (((n >> 11) & 1) << 2)
         ^ (((n >> 12) & 1) << 3) ^ (((n >> 13) & 1) << 4);
}

// ---------------- Pass R: std -> M, RY on E13..E0 (layer 0) ----------------
// n: [n0..n4]=(E0,E1,E10,E11,E12) [n5..n10]=(E2..E7) [n11..n13]=(E8,E9,E13)
#define R_LOAD(BLK, V) { int H = (BLK) & 63, b = (BLK) >> 6; \
  int base = (b << 18) + (H << 12); \
  _Pragma("unroll") for (int i = 0; i < 8; ++i) { \
    float4 w = src[base + (i << 8) + (((t >> 6) & 3) << 6) + (((t >> 8) & 1) << 11) + (t & 63)]; \
    (V)[i*4+0] = w.x; (V)[i*4+1] = w.y; (V)[i*4+2] = w.z; (V)[i*4+3] = w.w; } }

#define R_PH1(V) { \
  RYV_(V, csl, 1, 19); RYV_(V, csl, 2, 18); RYV_(V, csl, 4, 9); RYV_(V, csl, 8, 8); RYV_(V, csl, 16, 7); \
  int w1x = (t & 31) ^ ((t >> 5) & 1); \
  _Pragma("unroll") for (int m = 0; m < 32; ++m) lds[(t << 5) | (m ^ w1x)] = (V)[m]; }

#define R_PH2(V) { int tp = (t & 31) | (((t >> 5) & 1) << 10) | (((t >> 6) & 7) << 11); \
  int mt = mixR(tp); \
  _Pragma("unroll") for (int f = 0; f < 32; ++f) { int fc = f << 5; (V)[f] = lds[(tp | fc) ^ mt ^ mixR(fc)]; } \
  RYV_(V, csl, 1, 17); RYV_(V, csl, 2, 16); RYV_(V, csl, 4, 15); RYV_(V, csl, 8, 14); RYV_(V, csl, 16, 13); \
  _Pragma("unroll") for (int f = 0; f < 32; ++f) { int fc = f << 5; lds[(tp | fc) ^ mt ^ mixR(fc)] = (V)[f]; } }

#define R_PH3(V, BLK) { int tp = ((t & 1) << 2) | (((t >> 1) & 1) << 3) | (((t >> 2) & 1) << 4) \
             | (((t >> 3) & 1) << 5) | (((t >> 4) & 1) << 1) | (((t >> 5) & 1) << 0) \
             | (((t >> 6) & 7) << 6); \
  int mt = mixR(tp); \
  _Pragma("unroll") for (int p = 0; p < 32; ++p) { int fc = p << 9; (V)[p] = lds[(tp | fc) ^ mt ^ mixR(fc)]; } \
  RYV_(V, csl, 2, 12); RYV_(V, csl, 4, 11); RYV_(V, csl, 8, 10); RYV_(V, csl, 16, 6); \
  int H = (BLK) & 63, b = (BLK) >> 6; \
  int sb = (b << 18) + (H << 12) + (((t >> 6) & 7) << 6) + (t & 63); \
  _Pragma("unroll") for (int j = 0; j < 8; ++j) \
    dst[sb + (j << 9)] = make_float4((V)[4*j], (V)[4*j+1], (V)[4*j+2], (V)[4*j+3]); }

__global__ __launch_bounds__(512, 2) void pass_R(
    const float4* __restrict__ src, float4* __restrict__ dst,
    const float2* __restrict__ cs)
{
    __shared__ float lds[16384];
    const float2* csl = cs;                       // layer 0
    int t = threadIdx.x;
    int blk0 = blockIdx.x, blk1 = blockIdx.x + 512;
    float va[32], vb[32];

    R_LOAD(blk0, va); R_LOAD(blk1, vb);
    R_PH1(va); BAR();
    R_PH2(va); BAR();
    R_PH3(va, blk0); BAR();
    R_PH1(vb); BAR();
    R_PH2(vb); BAR();
    R_PH3(vb, blk1);
}

// ---------------- Pass A: M -> P ----------------
// n: [n0..n4]=(E6,E7,E17,E18,E19) [n5..n10]=(E10,E11,E12,E14,E15,E16)
//    [n11..n13]=(E8,E9,E13)
#define A_LOAD(BLK, V) { int G = (BLK) & 63, b = (BLK) >> 6; \
  int Gperm = ((G >> 2) & 1) | (((G >> 1) & 1) << 1) | ((G & 1) << 2) | (((G >> 3) & 7) << 3); \
  int lb = (b << 18) + (((t >> 6) & 7) << 9) + (Gperm << 3) + (t & 7); \
  int rg = ((t >> 3) & 7) << 12; \
  _Pragma("unroll") for (int i = 0; i < 8; ++i) { \
    float4 w = src[lb + ((i << 3) << 12) + rg]; \
    (V)[i*4+0] = w.x; (V)[i*4+1] = w.y; (V)[i*4+2] = w.z; (V)[i*4+3] = w.w; } }

#define A_PH1(V) { \
  RYV_(V, csl, 16, 0); RYV_(V, csl, 8, 1); RYV_(V, csl, 4, 2); \
  if (FULL) { RYV_(V, csl, 2, 12); RYV_(V, csl, 1, 13); } \
  int w1x = (t & 31) ^ ((t >> 5) & 1) ^ (((t >> 6) & 1) << 3) \
          ^ (((t >> 7) & 1) << 4) ^ (((t >> 8) & 1) << 4); \
  _Pragma("unroll") for (int m = 0; m < 32; ++m) lds[(t << 5) | (m ^ w1x)] = (V)[m]; }

#define A_PH2(V) { int tp = (t & 3) | (((t >> 2) & 1) << 7) | (((t >> 3) & 1) << 11) \
             | (((t >> 4) & 1) << 12) | (((t >> 5) & 1) << 13) | (((t >> 6) & 1) << 5) \
             | (((t >> 7) & 1) << 6) | (((t >> 8) & 1) << 8); \
  int mt = mixA(tp); \
  _Pragma("unroll") for (int f = 0; f < 32; ++f) { \
    int fc = ((f & 1) << 9) | (((f >> 1) & 1) << 10) | (((f >> 2) & 1) << 2) \
           | (((f >> 3) & 1) << 3) | (((f >> 4) & 1) << 4); \
    (V)[f] = lds[(tp | fc) ^ mt ^ mixA(fc)]; } \
  RYV_(V, csl, 1, 4); RYV_(V, csl, 2, 3); \
  CXV_(V, 16, 8); CXV_(V, 8, 4); CXV_(V, 4, 2); CXV_(V, 2, 1); \
  _Pragma("unroll") for (int f = 0; f < 32; ++f) { \
    int fc = ((f & 1) << 9) | (((f >> 1) & 1) << 10) | (((f >> 2) & 1) << 2) \
           | (((f >> 3) & 1) << 3) | (((f >> 4) & 1) << 4); \
    lds[(tp | fc) ^ mt ^ mixA(fc)] = (V)[f]; } }

#define A_PH3(V) { int tp = (t & 31) | (((t >> 5) & 1) << 9) | (((t >> 6) & 1) << 10) \
             | (((t >> 7) & 1) << 11) | (((t >> 8) & 1) << 12); \
  int mt = mixA(tp); \
  _Pragma("unroll") for (int f = 0; f < 32; ++f) { \
    int fc = ((f & 1) << 5) | (((f >> 1) & 1) << 6) | (((f >> 2) & 1) << 7) \
           | (((f >> 3) & 1) << 13) | (((f >> 4) & 1) << 8); \
    (V)[f] = lds[(tp | fc) ^ mt ^ mixA(fc)]; } \
  RYV_(V, csl, 16, 5); \
  if (FULL) { RYV_(V, csl, 8, 6); RYV_(V, csl, 4, 7); RYV_(V, csl, 2, 8); RYV_(V, csl, 1, 9); } \
  CXIV_(V, (t >> 5) & 1, 16); CXV_(V, 16, 8); CXV_(V, 8, 4); CXV_(V, 4, 2); CXV_(V, 2, 1); \
  _Pragma("unroll") for (int f = 0; f < 32; ++f) { \
    int fc = ((f & 1) << 5) | (((f >> 1) & 1) << 6) | (((f >> 2) & 1) << 7) \
           | (((f >> 3) & 1) << 13) | (((f >> 4) & 1) << 8); \
    lds[(tp | fc) ^ mt ^ mixA(fc)] = (V)[f]; } }

#define A_PH4(V, BLK) { int tp = ((t & 1) << 8) | (((t >> 1) & 1) << 9) | (((t >> 2) & 1) << 10) \
             | (((t >> 3) & 1) << 6) | (((t >> 4) & 1) << 7) | (((t >> 5) & 1) << 2) \
             | (((t >> 6) & 1) << 5) | (((t >> 7) & 1) << 3) | (((t >> 8) & 1) << 4); \
  int mt = mixA(tp); \
  _Pragma("unroll") for (int p = 0; p < 32; ++p) { \
    int fc = ((p & 1) << 0) | (((p >> 1) & 1) << 13) | (((p >> 2) & 1) << 1) \
           | (((p >> 3) & 1) << 11) | (((p >> 4) & 1) << 12); \
    (V)[p] = lds[(tp | fc) ^ mt ^ mixA(fc)]; } \
  if (FULL) { RYV_(V, csl, 16, 10); RYV_(V, csl, 8, 11); } \
  CXIV_(V, (t >> 6) & 1, 16); CXV_(V, 16, 8); CXV_(V, 8, 4); CXV_(V, 4, 1); \
  int G = (BLK) & 63, b = (BLK) >> 6; \
  int sb = (b << 18) + (G << 12) + t; \
  _Pragma("unroll") for (int j = 0; j < 8; ++j) \
    dst[sb + (j << 9)] = make_float4((V)[4*j], (V)[4*j+1], (V)[4*j+2], (V)[4*j+3]); }

template <bool FULL>
__global__ __launch_bounds__(512, 2) void pass_A(
    const float4* __restrict__ src, float4* __restrict__ dst,
    const float2* __restrict__ cs, int layer)
{
    __shared__ float lds[16384];
    const float2* csl = cs + layer * 20;
    int t = threadIdx.x;
    int blk0 = blockIdx.x, blk1 = blockIdx.x + 512;
    float va[32], vb[32];

    A_LOAD(blk0, va); A_LOAD(blk1, vb);
    A_PH1(va); BAR();
    A_PH2(va); BAR();
    A_PH3(va); BAR();
    A_PH4(va, blk0); BAR();
    A_PH1(vb); BAR();
    A_PH2(vb); BAR();
    A_PH3(vb); BAR();
    A_PH4(vb, blk1);
}

// ---------------- Pass F: P -> Q ----------------
// n: [n0..n4]=(E6,E13,E17,E18,E19) [n5..n10]=(E14,E15,E16,E0,E1,E2)
//    [n11..n13]=(E3,E4,E5)
#define F_LOAD(BLK, V) { int W = (BLK) & 63, b = (BLK) >> 6; \
  int Wp = (((W >> 4) & 1) << 3) | (((W >> 5) & 1) << 4) | (((W >> 3) & 1) << 6) \
         | ((W & 1) << 9) | (((W >> 1) & 1) << 10) | (((W >> 2) & 1) << 11); \
  int lb = (((b << 6) | ((t >> 3) & 63)) << 12) + (t & 7) + Wp; \
  _Pragma("unroll") for (int i = 0; i < 8; ++i) { \
    float4 w = src[lb + ((i & 1) << 5) + (((i >> 1) & 1) << 7) + (((i >> 2) & 1) << 8)]; \
    (V)[i*4+0] = w.x; (V)[i*4+1] = w.y; (V)[i*4+2] = w.z; (V)[i*4+3] = w.w; } }

#define F_PH1(V) { \
  RYV_(V, csl2, 16, 0); RYV_(V, csl2, 8, 1); RYV_(V, csl2, 4, 2); RYV_(V, csl2, 2, 6); \
  CXV_(V, 16, 8); CXV_(V, 8, 4); \
  int w1x = (t & 31) ^ (((t >> 5) & 1) << 1) ^ (((t >> 6) & 1) << 2) \
          ^ (((t >> 7) & 1) << 3) ^ (((t >> 8) & 1) << 4); \
  _Pragma("unroll") for (int m = 0; m < 32; ++m) lds[(t << 5) | (m ^ w1x)] = (V)[m]; }

#define F_PH2(V) { int tp = (t & 31) | (((t >> 5) & 1) << 8) | (((t >> 6) & 1) << 5) \
             | (((t >> 7) & 1) << 6) | (((t >> 8) & 1) << 7); \
  int mt = mixF(tp); \
  _Pragma("unroll") for (int f = 0; f < 32; ++f) { int fc = f << 9; (V)[f] = lds[(tp | fc) ^ mt ^ mixF(fc)]; } \
  if (LOWRY) { RYV_(V, csl, 16, 14); RYV_(V, csl, 8, 15); RYV_(V, csl, 4, 16); RYV_(V, csl, 2, 17); RYV_(V, csl, 1, 18); } \
  CXIV_(V, t & 1, 16); CXV_(V, 16, 8); CXV_(V, 8, 4); CXV_(V, 4, 2); CXV_(V, 2, 1); \
  _Pragma("unroll") for (int f = 0; f < 32; ++f) { int fc = f << 9; lds[(tp | fc) ^ mt ^ mixF(fc)] = (V)[f]; } }

#define F_PH3(V, BLK) { int tp = ((t & 1) << 12) | (((t >> 1) & 1) << 13) | (((t >> 2) & 1) << 0) \
             | (((t >> 3) & 1) << 9) | (((t >> 4) & 1) << 10) | (((t >> 5) & 1) << 11) \
             | (((t >> 6) & 1) << 2) | (((t >> 7) & 1) << 3) | (((t >> 8) & 1) << 4); \
  int mt = mixF(tp); \
  _Pragma("unroll") for (int p = 0; p < 32; ++p) { \
    int fc = ((p & 1) << 8) | (((p >> 1) & 1) << 1) | (((p >> 2) & 1) << 5) \
           | (((p >> 3) & 1) << 6) | (((p >> 4) & 1) << 7); \
    (V)[p] = lds[(tp | fc) ^ mt ^ mixF(fc)]; } \
  if (LOWRY) { RYV_(V, csl, 1, 19); } \
  CXIV_(V, (t >> 3) & 1, 1); \
  RYV_(V, csl2, 16, 3); RYV_(V, csl2, 8, 4); RYV_(V, csl2, 4, 5); \
  CXIV_(V, (t >> 6) & 1, 16); CXV_(V, 16, 8); CXV_(V, 8, 4); CXV_(V, 4, 2); \
  int sb = ((BLK) << 12) + t; \
  _Pragma("unroll") for (int j = 0; j < 8; ++j) \
    dst[sb + (j << 9)] = make_float4((V)[4*j], (V)[4*j+1], (V)[4*j+2], (V)[4*j+3]); }

template <bool LOWRY>
__global__ __launch_bounds__(512, 2) void pass_F(
    const float4* __restrict__ src, float4* __restrict__ dst,
    const float2* __restrict__ cs, int layer)
{
    __shared__ float lds[16384];
    const float2* csl  = cs + layer * 20;         // layer l (low chain / low RY)
    const float2* csl2 = cs + (layer + 1) * 20;   // layer l+1 (hi RY + hi chain)
    int t = threadIdx.x;
    int blk0 = blockIdx.x, blk1 = blockIdx.x + 512;
    float va[32], vb[32];

    F_LOAD(blk0, va); F_LOAD(blk1, vb);
    F_PH1(va); BAR();
    F_PH2(va); BAR();
    F_PH3(va, blk0); BAR();
    F_PH1(vb); BAR();
    F_PH2(vb); BAR();
    F_PH3(vb, blk1);
}

// ---------------- Pass L: Q -> M (mid) or std+abs (fin) ----------------
// n: [n0..n4]=(E0,E13,E10,E11,E12) [n5..n10]=(E4,E5,E6,E1,E2,E3)
//    [n11..n13]=(E7,E8,E9)
#define L_LOAD(BLK, V) { int H = (BLK) & 63, b = (BLK) >> 6; \
  int Hp = (((H >> 3) & 7) << 6) | ((H & 7) << 9); \
  int rb = (b << 6) | ((t >> 6) & 7); \
  int lo = Hp + (t & 63); \
  _Pragma("unroll") for (int i = 0; i < 8; ++i) { \
    float4 w = src[((rb | (i << 3)) << 12) + lo]; \
    (V)[i*4+0] = w.x; (V)[i*4+1] = w.y; (V)[i*4+2] = w.z; (V)[i*4+3] = w.w; } }

#define L_PH1(V) { \
  RYV_(V, csl, 1, 19); RYV_(V, csl, 4, 9); RYV_(V, csl, 8, 8); RYV_(V, csl, 16, 7); \
  int w1x = (t & 31) ^ (((t >> 5) & 1) << 4) ^ (((t >> 6) & 1) << 2) \
          ^ (((t >> 7) & 1) << 3) ^ (((t >> 8) & 1) << 4); \
  _Pragma("unroll") for (int m = 0; m < 32; ++m) lds[(t << 5) | (m ^ w1x)] = (V)[m]; }

#define L_PH2(V) { int tp = (t & 3) | (((t >> 2) & 1) << 7) | (((t >> 3) & 1) << 8) \
             | (((t >> 4) & 1) << 9) | (((t >> 5) & 1) << 10) | (((t >> 6) & 1) << 5) \
             | (((t >> 7) & 1) << 6) | (((t >> 8) & 1) << 11); \
  int mt = mixL(tp); \
  _Pragma("unroll") for (int f = 0; f < 32; ++f) { \
    int fc = ((f & 1) << 12) | (((f >> 1) & 1) << 13) | (((f >> 2) & 1) << 2) \
           | (((f >> 3) & 1) << 3) | (((f >> 4) & 1) << 4); \
    (V)[f] = lds[(tp | fc) ^ mt ^ mixL(fc)]; } \
  RYV_(V, csl, 2, 10); RYV_(V, csl, 1, 11); \
  CXIV_(V, (t >> 1) & 1, 16); CXV_(V, 16, 8); CXV_(V, 8, 4); CXV_(V, 4, 2); CXV_(V, 2, 1); \
  _Pragma("unroll") for (int f = 0; f < 32; ++f) { \
    int fc = ((f & 1) << 12) | (((f >> 1) & 1) << 13) | (((f >> 2) & 1) << 2) \
           | (((f >> 3) & 1) << 3) | (((f >> 4) & 1) << 4); \
    lds[(tp | fc) ^ mt ^ mixL(fc)] = (V)[f]; } }

#define L_PH3(V) { int tp = (t & 31) | (((t >> 5) & 1) << 9) | (((t >> 6) & 1) << 8) \
             | (((t >> 7) & 1) << 12) | (((t >> 8) & 1) << 13); \
  int mt = mixL(tp); \
  _Pragma("unroll") for (int f = 0; f < 32; ++f) { \
    int fc = ((f & 1) << 10) | (((f >> 1) & 1) << 5) | (((f >> 2) & 1) << 6) \
           | (((f >> 3) & 1) << 7) | (((f >> 4) & 1) << 11); \
    (V)[f] = lds[(tp | fc) ^ mt ^ mixL(fc)]; } \
  RYV_(V, csl, 16, 12); RYV_(V, csl, 8, 13); RYV_(V, csl, 4, 14); RYV_(V, csl, 2, 15); RYV_(V, csl, 1, 16); \
  CXIV_(V, (t >> 7) & 1, 16); CXV_(V, 16, 8); CXV_(V, 8, 4); CXV_(V, 4, 2); CXV_(V, 2, 1); \
  _Pragma("unroll") for (int f = 0; f < 32; ++f) { \
    int fc = ((f & 1) << 10) | (((f >> 1) & 1) << 5) | (((f >> 2) & 1) << 6) \
           | (((f >> 3) & 1) << 7) | (((f >> 4) & 1) << 11); \
    lds[(tp | fc) ^ mt ^ mixL(fc)] = (V)[f]; } }

#define L_PH4(V, BLK) { int tp; \
  if (!FIN) \
    tp = ((t & 1) << 2) | (((t >> 1) & 1) << 3) | (((t >> 2) & 1) << 4) \
       | (((t >> 3) & 1) << 10) | (((t >> 4) & 1) << 5) | (((t >> 5) & 1) << 6) \
       | (((t >> 6) & 1) << 1) | (((t >> 7) & 1) << 12) | (((t >> 8) & 1) << 13); \
  else \
    tp = ((t & 1) << 10) | (((t >> 1) & 1) << 5) | (((t >> 2) & 1) << 6) \
       | (((t >> 3) & 1) << 12) | (((t >> 4) & 1) << 13) | (((t >> 5) & 1) << 2) \
       | (((t >> 6) & 1) << 1) | (((t >> 7) & 1) << 3) | (((t >> 8) & 1) << 4); \
  int mt = mixL(tp); \
  _Pragma("unroll") for (int u = 0; u < 32; ++u) { \
    int fc = ((u & 1) << 0) | (((u >> 1) & 1) << 8) | (((u >> 2) & 1) << 9) \
           | (((u >> 3) & 1) << 7) | (((u >> 4) & 1) << 11); \
    (V)[u] = lds[(tp | fc) ^ mt ^ mixL(fc)]; } \
  RYV_(V, csl, 4, 17); RYV_(V, csl, 2, 18); \
  { int e3 = FIN ? (t & 1) : ((t >> 3) & 1); \
    CXIV_(V, e3, 4); } \
  CXV_(V, 4, 2); CXV_(V, 2, 1); \
  if (!FIN) { \
    int sb = ((BLK) << 12) + (t & 7) + (((t >> 3) & 7) << 6) \
           + (((t >> 7) & 3) << 9) + (((t >> 6) & 1) << 11); \
    _Pragma("unroll") for (int g = 0; g < 8; ++g) { \
      int bu = ((g >> 2) & 1) | (((g >> 1) & 1) << 1) | ((g & 1) << 2); \
      dst[sb + (g << 3)] = make_float4((V)[bu], (V)[bu | 8], (V)[bu | 16], (V)[bu | 24]); \
    } \
  } else { \
    int sb = ((BLK) << 12) + ((t & 7) << 1) + (((t >> 3) & 7) << 6) \
           + (((t >> 7) & 1) << 9) + (((t >> 8) & 1) << 10) + (((t >> 6) & 1) << 11); \
    _Pragma("unroll") for (int g = 0; g < 8; ++g) { \
      int bu = ((g & 1) << 2) | (((g >> 1) & 1) << 3) | (((g >> 2) & 1) << 4); \
      dst[sb + (g & 1) + (((g >> 1) & 1) << 4) + (((g >> 2) & 1) << 5)] = \
        make_float4(fabsf((V)[bu]), fabsf((V)[bu | 1]), fabsf((V)[bu | 2]), fabsf((V)[bu | 3])); \
    } \
  } }

template <bool FIN>
__global__ __launch_bounds__(512, 2) void pass_L(
    const float4* __restrict__ src, float4* __restrict__ dst,
    const float2* __restrict__ cs, int layer)
{
    __shared__ float lds[16384];
    const float2* csl = cs + layer * 20;
    int t = threadIdx.x;
    int blk0 = blockIdx.x, blk1 = blockIdx.x + 512;
    float va[32], vb[32];

    L_LOAD(blk0, va); L_LOAD(blk1, vb);
    L_PH1(va); BAR();
    L_PH2(va); BAR();
    L_PH3(va); BAR();
    L_PH4(va, blk0); BAR();
    L_PH1(vb); BAR();
    L_PH2(vb); BAR();
    L_PH3(vb); BAR();
    L_PH4(vb, blk1);
}

extern "C" void kernel_launch(void* const* d_in, const int* in_sizes, int n_in,
                              void* d_out, int out_size, void* d_ws, size_t ws_size,
                              hipStream_t stream) {
    const float* x     = (const float*)d_in[0];   // (16, 2^20) f32, standard layout
    const float* theta = (const float*)d_in[1];   // (80,) f32
    float2* cs = (float2*)d_ws;                   // 80 (cos,sin) pairs
    float4* wsS = (float4*)((char*)d_ws + 4096);  // 64 MB scratch state
    float4* out = (float4*)d_out;

    cs_kernel<<<1, 128, 0, stream>>>(theta, cs);

    dim3 grid(512), block(512);
    pass_R<<<grid, block, 0, stream>>>((const float4*)x, out, cs);            // L0 lo-RY
    pass_A<false><<<grid, block, 0, stream>>>(out, wsS, cs, 0);               // L0 hi
    pass_F<false><<<grid, block, 0, stream>>>(wsS, out, cs, 0);               // L0 lo-chain + L1 hi
    pass_L<false><<<grid, block, 0, stream>>>(out, wsS, cs, 1);               // L1 lo
    pass_A<true><<<grid, block, 0, stream>>>(wsS, out, cs, 2);                // L2 hi (full RY)
    pass_F<true><<<grid, block, 0, stream>>>(out, wsS, cs, 2);                // L2 lo + L3 hi
    pass_L<true><<<grid, block, 0, stream>>>(wsS, out, cs, 3);                // L3 lo + abs
}

// Round 5
// 257.635 us; speedup vs baseline: 2.1558x; 1.3106x over previous
//
#include <hip/hip_runtime.h>
#include <hip/hip_fp16.h>
#include <math.h>

// Quantum circuit sim, 20 qubits, 4 layers, batch 16, purely-real f32 state.
// Element bit Ek <-> qubit q = 19-k. 7 fused passes, each pass = one kernel:
//   R : RY on E13..E0                       (layer 0)           std -> M
//   A : RY E19..E14(+E13..E6 if FULL) + CNOT chain (19,18)..(7,6)   M -> P
//   F : chain (6,5)..(1,0) [layer l] (+RY E5..E0 if LOWRY)
//       + RY E19..E13 + chain (19,18)..(14,13) [layer l+1]          P -> Q
//   L : RY E12..E0 + chain (13,12)..(1,0) (+abs if FIN)             Q -> M/std
// Schedule: R(0) A(0) F(0,1) L(1) A*(2) F*(2,3) L*(3).
// Identical phase/gate/swizzle math to the verified 282-us baseline
// (grid 1024, single tile per block, __syncthreads). ONLY change: the
// inter-pass M/P/Q scratch states are packed fp16 (uint2 = 4 halves at the
// SAME index the old float4 used, slot order preserved). Halves HBM write
// traffic (writes measurably stream to HBM: R4 WRITE_SIZE=65MB/pass) and
// shrinks the ping-pong set to 64MB so L3 absorbs reads. Input x (f32) and
// final |.| f32 output unchanged. 6 fp16 round-trips add ~1e-3 abs error.

__global__ void cs_kernel(const float* __restrict__ theta, float2* __restrict__ cs) {
    int i = threadIdx.x;
    if (i < 80) {
        float s, c;
        sincosf(theta[i] * 0.5f, &s, &c);
        cs[i] = make_float2(c, s);
    }
}

union H2U { __half2 h; unsigned u; };
__device__ __forceinline__ unsigned pk2(float a, float b) {
    H2U x; x.h = __float22half2_rn(make_float2(a, b)); return x.u;
}
__device__ __forceinline__ float2 upk2(unsigned u) {
    H2U x; x.u = u; return __half22float2(x.h);
}

// RY on fragment bit MASK with angle table TBL[Q]
#define RYT_(TBL, MASK, Q) { float2 _sc = (TBL)[(Q)]; float _c = _sc.x, _s = _sc.y; \
  _Pragma("unroll") for (int _m = 0; _m < 32; ++_m) if (!(_m & (MASK))) { \
    float _a = v[_m], _b = v[_m | (MASK)]; \
    v[_m] = _c*_a - _s*_b; v[_m | (MASK)] = _s*_a + _c*_b; } }

// CNOT: control mask CM, target mask TM, both in fragment
#define CX_(CM, TM) { _Pragma("unroll") for (int _m = 0; _m < 32; ++_m) \
  if ((_m & (CM)) && !(_m & (TM))) { float _t = v[_m]; v[_m] = v[_m|(TM)]; v[_m|(TM)] = _t; } }

// CNOT with control on a thread-index bit (COND), target mask TM in fragment
#define CXI_(COND, TM) { if (COND) { _Pragma("unroll") for (int _m = 0; _m < 32; ++_m) \
  if (!(_m & (TM))) { float _t = v[_m]; v[_m] = v[_m|(TM)]; v[_m|(TM)] = _t; } } }

__device__ __forceinline__ int mixR(int n) {
    return ((n >> 5) & 31) ^ ((n >> 10) & 1);
}
__device__ __forceinline__ int mixA(int n) {
    return ((n >> 5) & 31) ^ ((n >> 10) & 1) ^ (((n >> 11) & 1) << 3)
         ^ (((n >> 12) & 1) << 4) ^ (((n >> 13) & 1) << 4);
}
__device__ __forceinline__ int mixF(int n) {
    return ((n >> 5) & 31) ^ (((n >> 10) & 1) << 1) ^ (((n >> 11) & 1) << 2)
         ^ (((n >> 12) & 1) << 3) ^ (((n >> 13) & 1) << 4);
}
__device__ __forceinline__ int mixL(int n) {
    return ((n >> 5) & 31) ^ (((n >> 10) & 1) << 4) ^ (((n >> 11) & 1) << 2)
         ^ (((n >> 12) & 1) << 3) ^ (((n >> 13) & 1) << 4);
}

// ---------------- Pass R: std -> M, RY on E13..E0 (layer 0) ----------------
// n: [n0..n4]=(E0,E1,E10,E11,E12) [n5..n10]=(E2..E7) [n11..n13]=(E8,E9,E13)
__global__ __launch_bounds__(512, 4) void pass_R(
    const float4* __restrict__ src, uint2* __restrict__ dst,
    const float2* __restrict__ cs)
{
    __shared__ float lds[16384];
    const float2* csl = cs;                       // layer 0
    int t = threadIdx.x, blk = blockIdx.x;
    int H = blk & 63, b = blk >> 6;
    int base = (b << 18) + (H << 12);
    float v[32];

    // load (standard, f32): t[5:0]=E2..E7, t[7:6]=E8,E9, t[8]=E13; i=(E10,E11,E12)
#pragma unroll
    for (int i = 0; i < 8; ++i) {
        float4 w = src[base + (i << 8) + (((t >> 6) & 3) << 6) + (((t >> 8) & 1) << 11) + (t & 63)];
        v[i*4+0] = w.x; v[i*4+1] = w.y; v[i*4+2] = w.z; v[i*4+3] = w.w;
    }
    // r1: m=(E0,E1,E10,E11,E12) -> RY q19,q18,q9,q8,q7
    RYT_(csl, 1, 19); RYT_(csl, 2, 18); RYT_(csl, 4, 9); RYT_(csl, 8, 8); RYT_(csl, 16, 7);
    { int w1x = (t & 31) ^ ((t >> 5) & 1);
#pragma unroll
      for (int m = 0; m < 32; ++m) lds[(t << 5) | (m ^ w1x)] = v[m]; }
    __syncthreads();

    // r2: frag=(E2,E3,E4,E5,E6) -> RY q17,q16,q15,q14,q13
    { int tp = (t & 31) | (((t >> 5) & 1) << 10) | (((t >> 6) & 7) << 11);
      int mt = mixR(tp);
#pragma unroll
      for (int f = 0; f < 32; ++f) { int fc = f << 5; v[f] = lds[(tp | fc) ^ mt ^ mixR(fc)]; }
      RYT_(csl, 1, 17); RYT_(csl, 2, 16); RYT_(csl, 4, 15); RYT_(csl, 8, 14); RYT_(csl, 16, 13);
#pragma unroll
      for (int f = 0; f < 32; ++f) { int fc = f << 5; lds[(tp | fc) ^ mt ^ mixR(fc)] = v[f]; } }
    __syncthreads();

    // r3: p=(E6,E7,E8,E9,E13) -> RY q12(2),q11(4),q10(8),q6(16)
    { int tp = ((t & 1) << 2) | (((t >> 1) & 1) << 3) | (((t >> 2) & 1) << 4)
             | (((t >> 3) & 1) << 5) | (((t >> 4) & 1) << 1) | (((t >> 5) & 1) << 0)
             | (((t >> 6) & 7) << 6);
      int mt = mixR(tp);
#pragma unroll
      for (int p = 0; p < 32; ++p) { int fc = p << 9; v[p] = lds[(tp | fc) ^ mt ^ mixR(fc)]; }
      RYT_(csl, 2, 12); RYT_(csl, 4, 11); RYT_(csl, 8, 10); RYT_(csl, 16, 6);
      // store -> M (fp16): slot k of idx = k-th float of old float4
      int sb = base + (((t >> 6) & 7) << 6) + (t & 63);
#pragma unroll
      for (int j = 0; j < 8; ++j)
        dst[sb + (j << 9)] = make_uint2(pk2(v[4*j], v[4*j+1]), pk2(v[4*j+2], v[4*j+3])); }
}

// ---------------- Pass A: M -> P ----------------
// n: [n0..n4]=(E6,E7,E17,E18,E19) [n5..n10]=(E10,E11,E12,E14,E15,E16)
//    [n11..n13]=(E8,E9,E13)
template <bool FULL>
__global__ __launch_bounds__(512, 4) void pass_A(
    const uint2* __restrict__ src, uint2* __restrict__ dst,
    const float2* __restrict__ cs, int layer)
{
    __shared__ float lds[16384];
    const float2* csl = cs + layer * 20;
    int t = threadIdx.x, blk = blockIdx.x;
    int G = blk & 63, b = blk >> 6;
    int Gperm = ((G >> 2) & 1) | (((G >> 1) & 1) << 1) | ((G & 1) << 2) | (((G >> 3) & 7) << 3);
    float v[32];

    // load from M (fp16)
    { int lb = (b << 18) + (((t >> 6) & 7) << 9) + (Gperm << 3) + (t & 7);
      int rg = ((t >> 3) & 7) << 12;
#pragma unroll
      for (int i = 0; i < 8; ++i) {
        uint2 w = src[lb + ((i << 3) << 12) + rg];
        float2 lo = upk2(w.x), hi = upk2(w.y);
        v[i*4+0] = lo.x; v[i*4+1] = lo.y; v[i*4+2] = hi.x; v[i*4+3] = hi.y;
      } }
    // r1: m=(E6,E7,E17,E18,E19): RY q0(16),q1(8),q2(4); FULL: q12(2),q13(1)
    RYT_(csl, 16, 0); RYT_(csl, 8, 1); RYT_(csl, 4, 2);
    if (FULL) { RYT_(csl, 2, 12); RYT_(csl, 1, 13); }
    { int w1x = (t & 31) ^ ((t >> 5) & 1) ^ (((t >> 6) & 1) << 3)
              ^ (((t >> 7) & 1) << 4) ^ (((t >> 8) & 1) << 4);
#pragma unroll
      for (int m = 0; m < 32; ++m) lds[(t << 5) | (m ^ w1x)] = v[m]; }
    __syncthreads();

    // r2: frag=(E15,E16,E17,E18,E19): RY q4(1),q3(2); links (19,18)..(16,15)
    { int tp = (t & 3) | (((t >> 2) & 1) << 7) | (((t >> 3) & 1) << 11)
             | (((t >> 4) & 1) << 12) | (((t >> 5) & 1) << 13) | (((t >> 6) & 1) << 5)
             | (((t >> 7) & 1) << 6) | (((t >> 8) & 1) << 8);
      int mt = mixA(tp);
#pragma unroll
      for (int f = 0; f < 32; ++f) {
        int fc = ((f & 1) << 9) | (((f >> 1) & 1) << 10) | (((f >> 2) & 1) << 2)
               | (((f >> 3) & 1) << 3) | (((f >> 4) & 1) << 4);
        v[f] = lds[(tp | fc) ^ mt ^ mixA(fc)]; }
      RYT_(csl, 1, 4); RYT_(csl, 2, 3);
      CX_(16, 8); CX_(8, 4); CX_(4, 2); CX_(2, 1);
#pragma unroll
      for (int f = 0; f < 32; ++f) {
        int fc = ((f & 1) << 9) | (((f >> 1) & 1) << 10) | (((f >> 2) & 1) << 2)
               | (((f >> 3) & 1) << 3) | (((f >> 4) & 1) << 4);
        lds[(tp | fc) ^ mt ^ mixA(fc)] = v[f]; } }
    __syncthreads();

    // r3: frag=(E10,E11,E12,E13,E14): RY q5(16); FULL q6(8),q7(4),q8(2),q9(1)
    //     links (15,14)[idx],(14,13),(13,12),(12,11),(11,10)
    { int tp = (t & 31) | (((t >> 5) & 1) << 9) | (((t >> 6) & 1) << 10)
             | (((t >> 7) & 1) << 11) | (((t >> 8) & 1) << 12);
      int mt = mixA(tp);
#pragma unroll
      for (int f = 0; f < 32; ++f) {
        int fc = ((f & 1) << 5) | (((f >> 1) & 1) << 6) | (((f >> 2) & 1) << 7)
               | (((f >> 3) & 1) << 13) | (((f >> 4) & 1) << 8);
        v[f] = lds[(tp | fc) ^ mt ^ mixA(fc)]; }
      RYT_(csl, 16, 5);
      if (FULL) { RYT_(csl, 8, 6); RYT_(csl, 4, 7); RYT_(csl, 2, 8); RYT_(csl, 1, 9); }
      CXI_((t >> 5) & 1, 16); CX_(16, 8); CX_(8, 4); CX_(4, 2); CX_(2, 1);
#pragma unroll
      for (int f = 0; f < 32; ++f) {
        int fc = ((f & 1) << 5) | (((f >> 1) & 1) << 6) | (((f >> 2) & 1) << 7)
               | (((f >> 3) & 1) << 13) | (((f >> 4) & 1) << 8);
        lds[(tp | fc) ^ mt ^ mixA(fc)] = v[f]; } }
    __syncthreads();

    // r4: p=(E6,E13,E7,E8,E9): FULL RY q10(16),q11(8);
    //     links (10,9)[idx t4[6]],(9,8):16->8,(8,7):8->4,(7,6):4->1
    { int tp = ((t & 1) << 8) | (((t >> 1) & 1) << 9) | (((t >> 2) & 1) << 10)
             | (((t >> 3) & 1) << 6) | (((t >> 4) & 1) << 7) | (((t >> 5) & 1) << 2)
             | (((t >> 6) & 1) << 5) | (((t >> 7) & 1) << 3) | (((t >> 8) & 1) << 4);
      int mt = mixA(tp);
#pragma unroll
      for (int p = 0; p < 32; ++p) {
        int fc = ((p & 1) << 0) | (((p >> 1) & 1) << 13) | (((p >> 2) & 1) << 1)
               | (((p >> 3) & 1) << 11) | (((p >> 4) & 1) << 12);
        v[p] = lds[(tp | fc) ^ mt ^ mixA(fc)]; }
      if (FULL) { RYT_(csl, 16, 10); RYT_(csl, 8, 11); }
      CXI_((t >> 6) & 1, 16); CX_(16, 8); CX_(8, 4); CX_(4, 1);
      // store -> P (fp16): f4-slot index = b<<18 | G<<12 | j<<9 | t
      int sb = (b << 18) + (G << 12) + t;
#pragma unroll
      for (int j = 0; j < 8; ++j)
        dst[sb + (j << 9)] = make_uint2(pk2(v[4*j], v[4*j+1]), pk2(v[4*j+2], v[4*j+3])); }
}

// ---------------- Pass F: P -> Q ----------------
// n: [n0..n4]=(E6,E13,E17,E18,E19) [n5..n10]=(E14,E15,E16,E0,E1,E2)
//    [n11..n13]=(E3,E4,E5)
template <bool LOWRY>
__global__ __launch_bounds__(512, 4) void pass_F(
    const uint2* __restrict__ src, uint2* __restrict__ dst,
    const float2* __restrict__ cs, int layer)
{
    __shared__ float lds[16384];
    const float2* csl  = cs + layer * 20;         // layer l (low chain / low RY)
    const float2* csl2 = cs + (layer + 1) * 20;   // layer l+1 (hi RY + hi chain)
    int t = threadIdx.x, blk = blockIdx.x;
    int W = blk & 63, b = blk >> 6;
    int Wp = (((W >> 4) & 1) << 3) | (((W >> 5) & 1) << 4) | (((W >> 3) & 1) << 6)
           | ((W & 1) << 9) | (((W >> 1) & 1) << 10) | (((W >> 2) & 1) << 11);
    float v[32];

    // load from P (fp16)
    { int lb = (((b << 6) | ((t >> 3) & 63)) << 12) + (t & 7) + Wp;
#pragma unroll
      for (int i = 0; i < 8; ++i) {
        uint2 w = src[lb + ((i & 1) << 5) + (((i >> 1) & 1) << 7) + (((i >> 2) & 1) << 8)];
        float2 lo = upk2(w.x), hi = upk2(w.y);
        v[i*4+0] = lo.x; v[i*4+1] = lo.y; v[i*4+2] = hi.x; v[i*4+3] = hi.y;
      } }
    // r1: m=(E6,E13,E17,E18,E19): RY+1 q0(16),q1(8),q2(4),q6(2); links+1 (19,18),(18,17)
    RYT_(csl2, 16, 0); RYT_(csl2, 8, 1); RYT_(csl2, 4, 2); RYT_(csl2, 2, 6);
    CX_(16, 8); CX_(8, 4);
    { int w1x = (t & 31) ^ (((t >> 5) & 1) << 1) ^ (((t >> 6) & 1) << 2)
              ^ (((t >> 7) & 1) << 3) ^ (((t >> 8) & 1) << 4);
#pragma unroll
      for (int m = 0; m < 32; ++m) lds[(t << 5) | (m ^ w1x)] = v[m]; }
    __syncthreads();

    // r2: frag=(E1,E2,E3,E4,E5): [LOWRY q14(16)..q18(1)]; links_l (6,5)[idx]..(2,1)
    { int tp = (t & 31) | (((t >> 5) & 1) << 8) | (((t >> 6) & 1) << 5)
             | (((t >> 7) & 1) << 6) | (((t >> 8) & 1) << 7);
      int mt = mixF(tp);
#pragma unroll
      for (int f = 0; f < 32; ++f) { int fc = f << 9; v[f] = lds[(tp | fc) ^ mt ^ mixF(fc)]; }
      if (LOWRY) { RYT_(csl, 16, 14); RYT_(csl, 8, 15); RYT_(csl, 4, 16); RYT_(csl, 2, 17); RYT_(csl, 1, 18); }
      CXI_(t & 1, 16); CX_(16, 8); CX_(8, 4); CX_(4, 2); CX_(2, 1);
#pragma unroll
      for (int f = 0; f < 32; ++f) { int fc = f << 9; lds[(tp | fc) ^ mt ^ mixF(fc)] = v[f]; } }
    __syncthreads();

    // r3: p=(E0,E13,E14,E15,E16): [LOWRY q19(1)]; link_l (1,0)[idx t3[3]];
    //     RY+1 q3(16),q4(8),q5(4); links+1 (17,16)[idx t3[6]],(16,15),(15,14),(14,13)
    { int tp = ((t & 1) << 12) | (((t >> 1) & 1) << 13) | (((t >> 2) & 1) << 0)
             | (((t >> 3) & 1) << 9) | (((t >> 4) & 1) << 10) | (((t >> 5) & 1) << 11)
             | (((t >> 6) & 1) << 2) | (((t >> 7) & 1) << 3) | (((t >> 8) & 1) << 4);
      int mt = mixF(tp);
#pragma unroll
      for (int p = 0; p < 32; ++p) {
        int fc = ((p & 1) << 8) | (((p >> 1) & 1) << 1) | (((p >> 2) & 1) << 5)
               | (((p >> 3) & 1) << 6) | (((p >> 4) & 1) << 7);
        v[p] = lds[(tp | fc) ^ mt ^ mixF(fc)]; }
      if (LOWRY) { RYT_(csl, 1, 19); }
      CXI_((t >> 3) & 1, 1);
      RYT_(csl2, 16, 3); RYT_(csl2, 8, 4); RYT_(csl2, 4, 5);
      CXI_((t >> 6) & 1, 16); CX_(16, 8); CX_(8, 4); CX_(4, 2);
      // store -> Q (fp16): f4-slot index = blk<<12 | j<<9 | t
      int sb = (blk << 12) + t;
#pragma unroll
      for (int j = 0; j < 8; ++j)
        dst[sb + (j << 9)] = make_uint2(pk2(v[4*j], v[4*j+1]), pk2(v[4*j+2], v[4*j+3])); }
}

// ---------------- Pass L: Q -> M (mid, fp16) or std+abs (fin, f32) ----------------
// n: [n0..n4]=(E0,E13,E10,E11,E12) [n5..n10]=(E4,E5,E6,E1,E2,E3)
//    [n11..n13]=(E7,E8,E9)
template <bool FIN>
__global__ __launch_bounds__(512, 4) void pass_L(
    const uint2* __restrict__ src, float4* __restrict__ dstf,
    uint2* __restrict__ dsth, const float2* __restrict__ cs, int layer)
{
    __shared__ float lds[16384];
    const float2* csl = cs + layer * 20;
    int t = threadIdx.x, blk = blockIdx.x;
    int H = blk & 63, b = blk >> 6;
    int Hp = (((H >> 3) & 7) << 6) | ((H & 7) << 9);
    float v[32];

    // load from Q (fp16)
    { int rb = (b << 6) | ((t >> 6) & 7);
      int lo = Hp + (t & 63);
#pragma unroll
      for (int i = 0; i < 8; ++i) {
        uint2 w = src[((rb | (i << 3)) << 12) + lo];
        float2 l2 = upk2(w.x), h2 = upk2(w.y);
        v[i*4+0] = l2.x; v[i*4+1] = l2.y; v[i*4+2] = h2.x; v[i*4+3] = h2.y;
      } }
    // r1: m=(E0,E13,E10,E11,E12): RY q19(1),q9(4),q8(8),q7(16)
    RYT_(csl, 1, 19); RYT_(csl, 4, 9); RYT_(csl, 8, 8); RYT_(csl, 16, 7);
    { int w1x = (t & 31) ^ (((t >> 5) & 1) << 4) ^ (((t >> 6) & 1) << 2)
              ^ (((t >> 7) & 1) << 3) ^ (((t >> 8) & 1) << 4);
#pragma unroll
      for (int m = 0; m < 32; ++m) lds[(t << 5) | (m ^ w1x)] = v[m]; }
    __syncthreads();

    // r2: frag=(E8,E9,E10,E11,E12): RY q10(2),q11(1);
    //     links (13,12)[idx t2[1]],(12,11),(11,10),(10,9),(9,8)
    { int tp = (t & 3) | (((t >> 2) & 1) << 7) | (((t >> 3) & 1) << 8)
             | (((t >> 4) & 1) << 9) | (((t >> 5) & 1) << 10) | (((t >> 6) & 1) << 5)
             | (((t >> 7) & 1) << 6) | (((t >> 8) & 1) << 11);
      int mt = mixL(tp);
#pragma unroll
      for (int f = 0; f < 32; ++f) {
        int fc = ((f & 1) << 12) | (((f >> 1) & 1) << 13) | (((f >> 2) & 1) << 2)
               | (((f >> 3) & 1) << 3) | (((f >> 4) & 1) << 4);
        v[f] = lds[(tp | fc) ^ mt ^ mixL(fc)]; }
      RYT_(csl, 2, 10); RYT_(csl, 1, 11);
      CXI_((t >> 1) & 1, 16); CX_(16, 8); CX_(8, 4); CX_(4, 2); CX_(2, 1);
#pragma unroll
      for (int f = 0; f < 32; ++f) {
        int fc = ((f & 1) << 12) | (((f >> 1) & 1) << 13) | (((f >> 2) & 1) << 2)
               | (((f >> 3) & 1) << 3) | (((f >> 4) & 1) << 4);
        lds[(tp | fc) ^ mt ^ mixL(fc)] = v[f]; } }
    __syncthreads();

    // r3: frag=(E3,E4,E5,E6,E7): RY q12(16),q13(8),q14(4),q15(2),q16(1);
    //     links (8,7)[idx t3[7]],(7,6),(6,5),(5,4),(4,3)
    { int tp = (t & 31) | (((t >> 5) & 1) << 9) | (((t >> 6) & 1) << 8)
             | (((t >> 7) & 1) << 12) | (((t >> 8) & 1) << 13);
      int mt = mixL(tp);
#pragma unroll
      for (int f = 0; f < 32; ++f) {
        int fc = ((f & 1) << 10) | (((f >> 1) & 1) << 5) | (((f >> 2) & 1) << 6)
               | (((f >> 3) & 1) << 7) | (((f >> 4) & 1) << 11);
        v[f] = lds[(tp | fc) ^ mt ^ mixL(fc)]; }
      RYT_(csl, 16, 12); RYT_(csl, 8, 13); RYT_(csl, 4, 14); RYT_(csl, 2, 15); RYT_(csl, 1, 16);
      CXI_((t >> 7) & 1, 16); CX_(16, 8); CX_(8, 4); CX_(4, 2); CX_(2, 1);
#pragma unroll
      for (int f = 0; f < 32; ++f) {
        int fc = ((f & 1) << 10) | (((f >> 1) & 1) << 5) | (((f >> 2) & 1) << 6)
               | (((f >> 3) & 1) << 7) | (((f >> 4) & 1) << 11);
        lds[(tp | fc) ^ mt ^ mixL(fc)] = v[f]; } }
    __syncthreads();

    // r4: u=(E0,E1,E2,E6,E7): RY q17(4),q18(2); links (3,2)[idx],(2,1),(1,0)
    { int tp;
      if (!FIN)
        tp = ((t & 1) << 2) | (((t >> 1) & 1) << 3) | (((t >> 2) & 1) << 4)
           | (((t >> 3) & 1) << 10) | (((t >> 4) & 1) << 5) | (((t >> 5) & 1) << 6)
           | (((t >> 6) & 1) << 1) | (((t >> 7) & 1) << 12) | (((t >> 8) & 1) << 13);
      else
        tp = ((t & 1) << 10) | (((t >> 1) & 1) << 5) | (((t >> 2) & 1) << 6)
           | (((t >> 3) & 1) << 12) | (((t >> 4) & 1) << 13) | (((t >> 5) & 1) << 2)
           | (((t >> 6) & 1) << 1) | (((t >> 7) & 1) << 3) | (((t >> 8) & 1) << 4);
      int mt = mixL(tp);
#pragma unroll
      for (int u = 0; u < 32; ++u) {
        int fc = ((u & 1) << 0) | (((u >> 1) & 1) << 8) | (((u >> 2) & 1) << 9)
               | (((u >> 3) & 1) << 7) | (((u >> 4) & 1) << 11);
        v[u] = lds[(tp | fc) ^ mt ^ mixL(fc)]; }
      RYT_(csl, 4, 17); RYT_(csl, 2, 18);
      { int e3 = FIN ? (t & 1) : ((t >> 3) & 1);
        CXI_(e3, 4); }
      CX_(4, 2); CX_(2, 1);
      if (!FIN) {
        // store -> M (fp16)
        int sb = (blk << 12) + (t & 7) + (((t >> 3) & 7) << 6)
               + (((t >> 7) & 3) << 9) + (((t >> 6) & 1) << 11);
#pragma unroll
        for (int g = 0; g < 8; ++g) {
          int bu = ((g >> 2) & 1) | (((g >> 1) & 1) << 1) | ((g & 1) << 2);
          dsth[sb + (g << 3)] = make_uint2(pk2(v[bu], v[bu | 8]), pk2(v[bu | 16], v[bu | 24]));
        }
      } else {
        // store -> standard f32, with abs
        int sb = (blk << 12) + ((t & 7) << 1) + (((t >> 3) & 7) << 6)
               + (((t >> 7) & 1) << 9) + (((t >> 8) & 1) << 10) + (((t >> 6) & 1) << 11);
#pragma unroll
        for (int g = 0; g < 8; ++g) {
          int bu = ((g & 1) << 2) | (((g >> 1) & 1) << 3) | (((g >> 2) & 1) << 4);
          dstf[sb + (g & 1) + (((g >> 1) & 1) << 4) + (((g >> 2) & 1) << 5)] =
            make_float4(fabsf(v[bu]), fabsf(v[bu | 1]), fabsf(v[bu | 2]), fabsf(v[bu | 3]));
        }
      } }
}

extern "C" void kernel_launch(void* const* d_in, const int* in_sizes, int n_in,
                              void* d_out, int out_size, void* d_ws, size_t ws_size,
                              hipStream_t stream) {
    const float* x     = (const float*)d_in[0];   // (16, 2^20) f32, standard layout
    const float* theta = (const float*)d_in[1];   // (80,) f32
    float2* cs = (float2*)d_ws;                   // 80 (cos,sin) pairs
    uint2* wsH = (uint2*)((char*)d_ws + 4096);    // 32 MB fp16 scratch state
    uint2* outH = (uint2*)d_out;                  // out buffer doubles as fp16 scratch
    float4* outF = (float4*)d_out;                // final f32 output view

    cs_kernel<<<1, 128, 0, stream>>>(theta, cs);

    dim3 grid(1024), block(512);
    pass_R<<<grid, block, 0, stream>>>((const float4*)x, outH, cs);              // L0 lo-RY
    pass_A<false><<<grid, block, 0, stream>>>(outH, wsH, cs, 0);                 // L0 hi
    pass_F<false><<<grid, block, 0, stream>>>(wsH, outH, cs, 0);                 // L0 lo-chain + L1 hi
    pass_L<false><<<grid, block, 0, stream>>>(outH, nullptr, wsH, cs, 1);        // L1 lo
    pass_A<true><<<grid, block, 0, stream>>>(wsH, outH, cs, 2);                  // L2 hi (full RY)
    pass_F<true><<<grid, block, 0, stream>>>(outH, wsH, cs, 2);                  // L2 lo + L3 hi
    pass_L<true><<<grid, block, 0, stream>>>(wsH, outF, nullptr, cs, 3);         // L3 lo + abs
}